// Round 3
// baseline (19043.588 us; speedup 1.0000x reference)
//
#include <hip/hip_runtime.h>
#include <math.h>

#define B 512
#define S 64
#define T 32
#define E 512
#define H 1024
#define VOUTD 128
#define H2 (2*H)
#define H3 (3*H)
#define H6 (6*H)

typedef unsigned short ushortT;
typedef unsigned int uintT;
typedef __attribute__((ext_vector_type(8))) short short8;
typedef __attribute__((ext_vector_type(4))) float floatx4;

__device__ __forceinline__ float sigmoidf_(float x) { return 1.0f / (1.0f + expf(-x)); }

// ===========================================================================
// Split fp32 -> bf16 hi/lo planes. hi = trunc16(x), lo = trunc16(x - hi).
// ===========================================================================
__global__ __launch_bounds__(256) void split_bf16(
    const float4* __restrict__ x, uint2* __restrict__ hi, uint2* __restrict__ lo, int n4)
{
    int i = blockIdx.x * 256 + threadIdx.x;
    if (i >= n4) return;
    float4 v = x[i];
    uintT ux = __float_as_uint(v.x), uy = __float_as_uint(v.y);
    uintT uz = __float_as_uint(v.z), uw = __float_as_uint(v.w);
    uintT lx = __float_as_uint(v.x - __uint_as_float(ux & 0xFFFF0000u)) >> 16;
    uintT ly = __float_as_uint(v.y - __uint_as_float(uy & 0xFFFF0000u)) >> 16;
    uintT lz = __float_as_uint(v.z - __uint_as_float(uz & 0xFFFF0000u)) >> 16;
    uintT lw = __float_as_uint(v.w - __uint_as_float(uw & 0xFFFF0000u)) >> 16;
    hi[i] = make_uint2((ux >> 16) | (uy & 0xFFFF0000u), (uz >> 16) | (uw & 0xFFFF0000u));
    lo[i] = make_uint2(lx | (ly << 16), lz | (lw << 16));
}

__global__ __launch_bounds__(256) void zero16(uint4* __restrict__ p, int n)
{
    int i = blockIdx.x * 256 + threadIdx.x;
    if (i < n) p[i] = make_uint4(0u, 0u, 0u, 0u);
}

// ===========================================================================
// Split-bf16 MFMA GEMM: C[M,N] = A @ W^T + bias (fp32-class accuracy).
// A given as bf16 hi/lo planes (lda elems per row). Optional row gather:
// if idx != null, A row r -> plane row idx[((m0+r)&511)*idxStride + sIdx],
// sIdx = (m0>=512) ? sBwd : sFwd. Weight/bias set per m-half (enc fwd/bwd fuse).
// Tiles: 128x128x32, 256 thr = 4 waves (2x2 wave grid).
// Staging: register round-trip (global_load_dwordx4 -> ds_write_b128) with the
// classic two-barrier LDS protocol — NO async global_load_lds (R2 post-timing
// divergence suspect). 3 MFMA terms: Ah*Bh + Ah*Bl + Al*Bh.
// ===========================================================================
__global__ __launch_bounds__(256) void gemm_mfma_split(
    const ushortT* __restrict__ Ahi, const ushortT* __restrict__ Alo, int lda,
    const int* __restrict__ idx, int idxStride, int sFwd, int sBwd,
    const ushortT* __restrict__ Whi_f, const ushortT* __restrict__ Wlo_f,
    const float* __restrict__ bias_f,
    const ushortT* __restrict__ Whi_b, const ushortT* __restrict__ Wlo_b,
    const float* __restrict__ bias_b,
    float* __restrict__ C, int N, int K)
{
    __shared__ ushortT sAh[128 * 32];
    __shared__ ushortT sAl[128 * 32];
    __shared__ ushortT sBh[128 * 32];
    __shared__ ushortT sBl[128 * 32];

    const int t    = threadIdx.x;
    const int lane = t & 63;
    const int w    = t >> 6;
    const int m0   = blockIdx.y * 128;
    const int n0   = blockIdx.x * 128;
    const bool bwd = (m0 >= B);
    const ushortT* Whi = bwd ? Whi_b : Whi_f;
    const ushortT* Wlo = bwd ? Wlo_b : Wlo_f;
    const float*  bias = bwd ? bias_b : bias_f;
    const int sIdx = bwd ? sBwd : sFwd;

    // Staging map: 16B chunk c = li*256 + t (li=0,1) covers tile row c>>2,
    // k-segment (c&3)*8 elems. LDS elem offset = c*8 (row-major 128x32).
    const ushortT* gAh[2]; const ushortT* gAl[2];
    const ushortT* gBh[2]; const ushortT* gBl[2];
    int ldsE[2];
#pragma unroll
    for (int li = 0; li < 2; ++li) {
        int c = li * 256 + t;
        int row = c >> 2;
        int segE = (c & 3) * 8;
        long long arow;
        if (idx) arow = idx[((m0 + row) & (B - 1)) * idxStride + sIdx];
        else     arow = m0 + row;
        gAh[li] = Ahi + arow * (long long)lda + segE;
        gAl[li] = Alo + arow * (long long)lda + segE;
        long long nrow = n0 + row;
        gBh[li] = Whi + nrow * (long long)K + segE;
        gBl[li] = Wlo + nrow * (long long)K + segE;
        ldsE[li] = c * 8;
    }

    const int koff = (lane >> 4) * 8;       // quad * 8
    const int mrow = (w >> 1) * 64 + (lane & 15);
    const int ncol = (w & 1) * 64 + (lane & 15);

    floatx4 acc[4][4];
#pragma unroll
    for (int i = 0; i < 4; ++i)
#pragma unroll
        for (int j = 0; j < 4; ++j) acc[i][j] = (floatx4){0.f, 0.f, 0.f, 0.f};

    for (int k0 = 0; k0 < K; k0 += 32) {
        uint4 vAh[2], vAl[2], vBh[2], vBl[2];
#pragma unroll
        for (int li = 0; li < 2; ++li) {
            vAh[li] = *(const uint4*)(gAh[li] + k0);
            vAl[li] = *(const uint4*)(gAl[li] + k0);
            vBh[li] = *(const uint4*)(gBh[li] + k0);
            vBl[li] = *(const uint4*)(gBl[li] + k0);
        }
        __syncthreads();   // all waves done reading previous chunk's LDS
#pragma unroll
        for (int li = 0; li < 2; ++li) {
            *(uint4*)&sAh[ldsE[li]] = vAh[li];
            *(uint4*)&sAl[ldsE[li]] = vAl[li];
            *(uint4*)&sBh[ldsE[li]] = vBh[li];
            *(uint4*)&sBl[ldsE[li]] = vBl[li];
        }
        __syncthreads();   // lgkmcnt(0) drain: all writes visible

        short8 ah[4], al[4], bh[4], bl[4];
#pragma unroll
        for (int i = 0; i < 4; ++i) {
            ah[i] = *(const short8*)&sAh[(mrow + i * 16) * 32 + koff];
            al[i] = *(const short8*)&sAl[(mrow + i * 16) * 32 + koff];
            bh[i] = *(const short8*)&sBh[(ncol + i * 16) * 32 + koff];
            bl[i] = *(const short8*)&sBl[(ncol + i * 16) * 32 + koff];
        }
#pragma unroll
        for (int i = 0; i < 4; ++i)
#pragma unroll
            for (int j = 0; j < 4; ++j) {
                acc[i][j] = __builtin_amdgcn_mfma_f32_16x16x32_bf16(ah[i], bh[j], acc[i][j], 0, 0, 0);
                acc[i][j] = __builtin_amdgcn_mfma_f32_16x16x32_bf16(ah[i], bl[j], acc[i][j], 0, 0, 0);
                acc[i][j] = __builtin_amdgcn_mfma_f32_16x16x32_bf16(al[i], bh[j], acc[i][j], 0, 0, 0);
            }
    }

    // epilogue: C/D layout col=lane&15, row=(lane>>4)*4+reg
#pragma unroll
    for (int j = 0; j < 4; ++j) {
        int col = n0 + (w & 1) * 64 + j * 16 + (lane & 15);
        float bv = bias[col];
#pragma unroll
        for (int i = 0; i < 4; ++i) {
            int rowb = m0 + (w >> 1) * 64 + i * 16 + (lane >> 4) * 4;
#pragma unroll
            for (int r = 0; r < 4; ++r)
                C[(long long)(rowb + r) * N + col] = acc[i][j][r] + bv;
        }
    }
}

// ===========================================================================
// GRU gate: h = (1-z)*n + z*h in place; also emits bf16 hi/lo planes of h.
// ===========================================================================
__global__ __launch_bounds__(256) void gru_gate_split(
    const float* __restrict__ gi, const float* __restrict__ gh,
    float* __restrict__ h, ushortT* __restrict__ h_hi, ushortT* __restrict__ h_lo, int Hd)
{
    int i = blockIdx.x * blockDim.x + threadIdx.x;
    int b = i / Hd, j = i - b * Hd;
    const float* gib = gi + (size_t)b * 3 * Hd;
    const float* ghb = gh + (size_t)b * 3 * Hd;
    float r = sigmoidf_(gib[j] + ghb[j]);
    float z = sigmoidf_(gib[Hd + j] + ghb[Hd + j]);
    float n = tanhf(gib[2 * Hd + j] + r * ghb[2 * Hd + j]);
    float hnew = (1.0f - z) * n + z * h[i];
    h[i] = hnew;
    uintT u = __float_as_uint(hnew);
    h_hi[i] = (ushortT)(u >> 16);
    h_lo[i] = (ushortT)(__float_as_uint(hnew - __uint_as_float(u & 0xFFFF0000u)) >> 16);
}

// hh[b,0:H]=h_f[b], hh[b,H:2H]=h_b[b] (+ bf16 planes); tok[b]=tgt[b,0]
__global__ __launch_bounds__(256) void init_hh_tok_split(
    const float* __restrict__ h_f, const float* __restrict__ h_b,
    const int* __restrict__ tgt, float* __restrict__ hh,
    ushortT* __restrict__ hh_hi, ushortT* __restrict__ hh_lo, int* __restrict__ tok)
{
    int i = blockIdx.x * blockDim.x + threadIdx.x;   // over B*2H
    int b = i >> 11;
    int j = i & 2047;
    float v = (j < H) ? h_f[(size_t)b * H + j] : h_b[(size_t)b * H + (j - H)];
    hh[i] = v;
    uintT u = __float_as_uint(v);
    hh_hi[i] = (ushortT)(u >> 16);
    hh_lo[i] = (ushortT)(__float_as_uint(v - __uint_as_float(u & 0xFFFF0000u)) >> 16);
    if (j == 0) tok[b] = tgt[b * T];
}

// ===========================================================================
// logits = hh @ W_fc^T + b_fc (V=128); out[b,t,:]; tok[b]=argmax (first-idx ties)
// ===========================================================================
__global__ __launch_bounds__(128) void logits_argmax(
    const float* __restrict__ hh, const float* __restrict__ W_fc,
    const float* __restrict__ b_fc, float* __restrict__ out,
    int* __restrict__ tok, int t)
{
    __shared__ float sh[H2];
    __shared__ float svals[128];
    __shared__ int   sidx[128];
    const int b = blockIdx.x;
    const int v = threadIdx.x;
    const float* hrow = hh + (size_t)b * H2;
    for (int i = v; i < H2 / 4; i += 128)
        ((float4*)sh)[i] = ((const float4*)hrow)[i];
    __syncthreads();
    const float* wrow = W_fc + (size_t)v * H2;
    float acc = b_fc[v];
    for (int k = 0; k < H2; k += 4) {
        float4 w4 = *(const float4*)(wrow + k);
        float4 h4 = *(const float4*)(sh + k);
        acc += w4.x * h4.x + w4.y * h4.y + w4.z * h4.z + w4.w * h4.w;
    }
    out[(size_t)b * ((T - 1) * VOUTD) + (size_t)t * VOUTD + v] = acc;

    svals[v] = acc; sidx[v] = v;
    __syncthreads();
    for (int off = 64; off > 0; off >>= 1) {
        if (v < off) {
            float ov = svals[v + off]; int oi = sidx[v + off];
            if (ov > svals[v] || (ov == svals[v] && oi < sidx[v])) {
                svals[v] = ov; sidx[v] = oi;
            }
        }
        __syncthreads();
    }
    if (v == 0) tok[b] = sidx[0];
}

// ===========================================================================
// ----- fp32 fallback kernels (round-1 proven path, used only if ws small) ---
// ===========================================================================
__global__ __launch_bounds__(256) void gemm_bias(
    const float* __restrict__ Abase,
    const int* __restrict__ idx, int idxStride, int idxOff, int lda,
    const float* __restrict__ W, const float* __restrict__ bias,
    float* __restrict__ C, int N, int K)
{
    __shared__ float As[16][68];
    __shared__ float Ws[16][68];
    const int t = threadIdx.x;
    const int m0 = blockIdx.y * 64, n0 = blockIdx.x * 64;
    const int lr = t >> 2, lc = (t & 3) << 2;
    const int tx = t & 15, ty = t >> 4;
    const int tn0 = tx << 2, tm0 = ty << 2;
    const int arow = m0 + lr;
    const float* Aptr = idx ? (Abase + (size_t)idx[arow * idxStride + idxOff] * lda)
                            : (Abase + (size_t)arow * lda);
    const float* Wptr = W + (size_t)(n0 + lr) * K;
    float acc[4][4] = {{0.f}};
    for (int k0 = 0; k0 < K; k0 += 16) {
        float4 a4 = *(const float4*)(Aptr + k0 + lc);
        float4 w4 = *(const float4*)(Wptr + k0 + lc);
        __syncthreads();
        As[lc+0][lr] = a4.x; As[lc+1][lr] = a4.y; As[lc+2][lr] = a4.z; As[lc+3][lr] = a4.w;
        Ws[lc+0][lr] = w4.x; Ws[lc+1][lr] = w4.y; Ws[lc+2][lr] = w4.z; Ws[lc+3][lr] = w4.w;
        __syncthreads();
#pragma unroll
        for (int kk = 0; kk < 16; ++kk) {
            float4 av = *(const float4*)&As[kk][tm0];
            float4 wv = *(const float4*)&Ws[kk][tn0];
            float am[4] = {av.x, av.y, av.z, av.w};
            float wn[4] = {wv.x, wv.y, wv.z, wv.w};
#pragma unroll
            for (int i = 0; i < 4; ++i)
#pragma unroll
                for (int j = 0; j < 4; ++j) acc[i][j] += am[i] * wn[j];
        }
    }
    const float b0 = bias[n0+tn0], b1 = bias[n0+tn0+1], b2 = bias[n0+tn0+2], b3 = bias[n0+tn0+3];
#pragma unroll
    for (int i = 0; i < 4; ++i) {
        float4 o = make_float4(acc[i][0]+b0, acc[i][1]+b1, acc[i][2]+b2, acc[i][3]+b3);
        *(float4*)(C + (size_t)(m0 + tm0 + i) * N + n0 + tn0) = o;
    }
}

__global__ __launch_bounds__(256) void gemm_enc(
    const float* __restrict__ Abase, int lda, int K,
    const int* __restrict__ srcIdx, int s,
    const float* __restrict__ W1, const float* __restrict__ bias1,
    const float* __restrict__ W2, const float* __restrict__ bias2,
    float* __restrict__ C, int N)
{
    __shared__ float As[16][68];
    __shared__ float Ws[16][68];
    const int t = threadIdx.x;
    const int m0 = blockIdx.y * 64, n0 = blockIdx.x * 64;
    const bool bwd = (m0 >= B);
    const float* W = bwd ? W2 : W1;
    const float* bias = bwd ? bias2 : bias1;
    const int lr = t >> 2, lc = (t & 3) << 2;
    const int tx = t & 15, ty = t >> 4;
    const int tn0 = tx << 2, tm0 = ty << 2;
    const int arow = m0 + lr;
    const float* Aptr;
    if (srcIdx) {
        int r = arow & (B - 1);
        int sidx = bwd ? (S - 1 - s) : s;
        Aptr = Abase + (size_t)srcIdx[r * S + sidx] * lda;
    } else Aptr = Abase + (size_t)arow * lda;
    const float* Wptr = W + (size_t)(n0 + lr) * K;
    float acc[4][4] = {{0.f}};
    for (int k0 = 0; k0 < K; k0 += 16) {
        float4 a4 = *(const float4*)(Aptr + k0 + lc);
        float4 w4 = *(const float4*)(Wptr + k0 + lc);
        __syncthreads();
        As[lc+0][lr] = a4.x; As[lc+1][lr] = a4.y; As[lc+2][lr] = a4.z; As[lc+3][lr] = a4.w;
        Ws[lc+0][lr] = w4.x; Ws[lc+1][lr] = w4.y; Ws[lc+2][lr] = w4.z; Ws[lc+3][lr] = w4.w;
        __syncthreads();
#pragma unroll
        for (int kk = 0; kk < 16; ++kk) {
            float4 av = *(const float4*)&As[kk][tm0];
            float4 wv = *(const float4*)&Ws[kk][tn0];
            float am[4] = {av.x, av.y, av.z, av.w};
            float wn[4] = {wv.x, wv.y, wv.z, wv.w};
#pragma unroll
            for (int i = 0; i < 4; ++i)
#pragma unroll
                for (int j = 0; j < 4; ++j) acc[i][j] += am[i] * wn[j];
        }
    }
    const float b0 = bias[n0+tn0], b1 = bias[n0+tn0+1], b2 = bias[n0+tn0+2], b3 = bias[n0+tn0+3];
#pragma unroll
    for (int i = 0; i < 4; ++i) {
        float4 o = make_float4(acc[i][0]+b0, acc[i][1]+b1, acc[i][2]+b2, acc[i][3]+b3);
        *(float4*)(C + (size_t)(m0 + tm0 + i) * N + n0 + tn0) = o;
    }
}

__global__ __launch_bounds__(256) void gru_gate(
    const float* __restrict__ gi, const float* __restrict__ gh,
    float* __restrict__ h, int Hd)
{
    int i = blockIdx.x * blockDim.x + threadIdx.x;
    int b = i / Hd, j = i - b * Hd;
    const float* gib = gi + (size_t)b * 3 * Hd;
    const float* ghb = gh + (size_t)b * 3 * Hd;
    float r = sigmoidf_(gib[j] + ghb[j]);
    float z = sigmoidf_(gib[Hd + j] + ghb[Hd + j]);
    float n = tanhf(gib[2 * Hd + j] + r * ghb[2 * Hd + j]);
    h[i] = (1.0f - z) * n + z * h[i];
}

__global__ __launch_bounds__(256) void init_hh_tok(
    const float* __restrict__ h_f, const float* __restrict__ h_b,
    const int* __restrict__ tgt, float* __restrict__ hh, int* __restrict__ tok)
{
    int i = blockIdx.x * blockDim.x + threadIdx.x;
    int b = i >> 11, j = i & 2047;
    hh[i] = (j < H) ? h_f[(size_t)b * H + j] : h_b[(size_t)b * H + (j - H)];
    if (j == 0) tok[b] = tgt[b * T];
}

// ===========================================================================
extern "C" void kernel_launch(void* const* d_in, const int* in_sizes, int n_in,
                              void* d_out, int out_size, void* d_ws, size_t ws_size,
                              hipStream_t stream)
{
    const int*   src     = (const int*)d_in[0];
    const int*   tgt     = (const int*)d_in[1];
    const float* enc_emb = (const float*)d_in[2];
    const float* dec_emb = (const float*)d_in[3];
    const float* W_ih_f  = (const float*)d_in[4];
    const float* W_hh_f  = (const float*)d_in[5];
    const float* b_ih_f  = (const float*)d_in[6];
    const float* b_hh_f  = (const float*)d_in[7];
    const float* W_ih_b  = (const float*)d_in[8];
    const float* W_hh_b  = (const float*)d_in[9];
    const float* b_ih_b  = (const float*)d_in[10];
    const float* b_hh_b  = (const float*)d_in[11];
    const float* W_ih_d  = (const float*)d_in[12];
    const float* W_hh_d  = (const float*)d_in[13];
    const float* b_ih_d  = (const float*)d_in[14];
    const float* b_hh_d  = (const float*)d_in[15];
    const float* W_fc    = (const float*)d_in[16];
    const float* b_fc    = (const float*)d_in[17];
    float* out = (float*)d_out;

    // ---------------- workspace layout ----------------
    char* base = (char*)d_ws;
    size_t off = 0;
    auto alloc = [&](size_t bytes) { char* p = base + off; off += (bytes + 255) & ~(size_t)255; return p; };

    float*   hE     = (float*)  alloc((size_t)2 * B * H * 4);      // 1024 x 1024 fp32
    ushortT* hE_hi  = (ushortT*)alloc((size_t)2 * B * H * 2);      // contiguous with hE
    ushortT* hE_lo  = (ushortT*)alloc((size_t)2 * B * H * 2);
    float*   hh     = (float*)  alloc((size_t)B * H2 * 4);
    ushortT* hh_hi  = (ushortT*)alloc((size_t)B * H2 * 2);
    ushortT* hh_lo  = (ushortT*)alloc((size_t)B * H2 * 2);
    float*   giE    = (float*)  alloc((size_t)2 * B * H3 * 4);     // also decoder B x 6H
    float*   ghE    = (float*)  alloc((size_t)2 * B * H3 * 4);
    ushortT* embE_hi = (ushortT*)alloc((size_t)VOUTD * E * 2);
    ushortT* embE_lo = (ushortT*)alloc((size_t)VOUTD * E * 2);
    ushortT* embD_hi = (ushortT*)alloc((size_t)VOUTD * E * 2);
    ushortT* embD_lo = (ushortT*)alloc((size_t)VOUTD * E * 2);
    ushortT* Wihf_hi = (ushortT*)alloc((size_t)H3 * E * 2);
    ushortT* Wihf_lo = (ushortT*)alloc((size_t)H3 * E * 2);
    ushortT* Whhf_hi = (ushortT*)alloc((size_t)H3 * H * 2);
    ushortT* Whhf_lo = (ushortT*)alloc((size_t)H3 * H * 2);
    ushortT* Wihb_hi = (ushortT*)alloc((size_t)H3 * E * 2);
    ushortT* Wihb_lo = (ushortT*)alloc((size_t)H3 * E * 2);
    ushortT* Whhb_hi = (ushortT*)alloc((size_t)H3 * H * 2);
    ushortT* Whhb_lo = (ushortT*)alloc((size_t)H3 * H * 2);
    ushortT* Wihd_hi = (ushortT*)alloc((size_t)H6 * E * 2);
    ushortT* Wihd_lo = (ushortT*)alloc((size_t)H6 * E * 2);
    ushortT* Whhd_hi = (ushortT*)alloc((size_t)H6 * H2 * 2);
    ushortT* Whhd_lo = (ushortT*)alloc((size_t)H6 * H2 * 2);
    int*     tok    = (int*)    alloc((size_t)B * 4);
    size_t required = off;

    dim3 blk(256);

    if (ws_size >= required) {
        // =================== split-bf16 MFMA path ===================
        // zero hE + hE_hi + hE_lo (contiguous, all sizes 256-multiples) via kernel
        {
            size_t zbytes = (size_t)2 * B * H * 4 + 2 * ((size_t)2 * B * H * 2);
            int n16 = (int)(zbytes / 16);
            zero16<<<dim3((n16 + 255) / 256), blk, 0, stream>>>((uint4*)hE, n16);
        }

        auto split = [&](const float* x, ushortT* hi, ushortT* lo, size_t n) {
            int n4 = (int)(n / 4);
            split_bf16<<<dim3((n4 + 255) / 256), blk, 0, stream>>>(
                (const float4*)x, (uint2*)hi, (uint2*)lo, n4);
        };
        split(enc_emb, embE_hi, embE_lo, (size_t)VOUTD * E);
        split(dec_emb, embD_hi, embD_lo, (size_t)VOUTD * E);
        split(W_ih_f, Wihf_hi, Wihf_lo, (size_t)H3 * E);
        split(W_hh_f, Whhf_hi, Whhf_lo, (size_t)H3 * H);
        split(W_ih_b, Wihb_hi, Wihb_lo, (size_t)H3 * E);
        split(W_hh_b, Whhb_hi, Whhb_lo, (size_t)H3 * H);
        split(W_ih_d, Wihd_hi, Wihd_lo, (size_t)H6 * E);
        split(W_hh_d, Whhd_hi, Whhd_lo, (size_t)H6 * H2);

        // ---------------- Encoder: 64 steps, fwd+bwd fused ----------------
        dim3 grid_e(H3 / 128, (2 * B) / 128);        // 24 x 8
        dim3 grid_gate((2 * B * H) / 256);
        for (int s = 0; s < S; ++s) {
            gemm_mfma_split<<<grid_e, blk, 0, stream>>>(
                embE_hi, embE_lo, E, src, S, s, S - 1 - s,
                Wihf_hi, Wihf_lo, b_ih_f, Wihb_hi, Wihb_lo, b_ih_b,
                giE, H3, E);
            gemm_mfma_split<<<grid_e, blk, 0, stream>>>(
                hE_hi, hE_lo, H, nullptr, 0, 0, 0,
                Whhf_hi, Whhf_lo, b_hh_f, Whhb_hi, Whhb_lo, b_hh_b,
                ghE, H3, H);
            gru_gate_split<<<grid_gate, blk, 0, stream>>>(giE, ghE, hE, hE_hi, hE_lo, H);
        }

        init_hh_tok_split<<<dim3((B * H2) / 256), blk, 0, stream>>>(
            hE, hE + (size_t)B * H, tgt, hh, hh_hi, hh_lo, tok);

        // ---------------- Decoder: 31 steps, argmax feedback ----------------
        dim3 grid_d(H6 / 128, B / 128);              // 48 x 4
        dim3 grid_dgate((B * H2) / 256);
        for (int t = 0; t < T - 1; ++t) {
            gemm_mfma_split<<<grid_d, blk, 0, stream>>>(
                embD_hi, embD_lo, E, tok, 1, 0, 0,
                Wihd_hi, Wihd_lo, b_ih_d, Wihd_hi, Wihd_lo, b_ih_d,
                giE, H6, E);
            gemm_mfma_split<<<grid_d, blk, 0, stream>>>(
                hh_hi, hh_lo, H2, nullptr, 0, 0, 0,
                Whhd_hi, Whhd_lo, b_hh_d, Whhd_hi, Whhd_lo, b_hh_d,
                ghE, H6, H2);
            gru_gate_split<<<grid_dgate, blk, 0, stream>>>(giE, ghE, hh, hh_hi, hh_lo, H2);
            logits_argmax<<<dim3(B), dim3(128), 0, stream>>>(hh, W_fc, b_fc, out, tok, t);
        }
    } else {
        // =================== fp32 fallback (round-1 proven path) ===================
        {
            size_t zbytes = (size_t)2 * B * H * 4;
            int n16 = (int)(zbytes / 16);
            zero16<<<dim3((n16 + 255) / 256), blk, 0, stream>>>((uint4*)hE, n16);
        }
        dim3 grid_gi(H3 / 64, (2 * B) / 64);
        dim3 grid_gate((2 * B * H) / 256);
        for (int s = 0; s < S; ++s) {
            gemm_enc<<<grid_gi, blk, 0, stream>>>(enc_emb, E, E, src, s,
                                                  W_ih_f, b_ih_f, W_ih_b, b_ih_b, giE, H3);
            gemm_enc<<<grid_gi, blk, 0, stream>>>(hE, H, H, nullptr, 0,
                                                  W_hh_f, b_hh_f, W_hh_b, b_hh_b, ghE, H3);
            gru_gate<<<grid_gate, blk, 0, stream>>>(giE, ghE, hE, H);
        }
        init_hh_tok<<<dim3((B * H2) / 256), blk, 0, stream>>>(hE, hE + (size_t)B * H, tgt, hh, tok);
        dim3 grid_d(H6 / 64, B / 64);
        dim3 grid_dgate((B * H2) / 256);
        for (int t = 0; t < T - 1; ++t) {
            gemm_bias<<<grid_d, blk, 0, stream>>>(dec_emb, tok, 1, 0, E,
                                                  W_ih_d, b_ih_d, giE, H6, E);
            gemm_bias<<<grid_d, blk, 0, stream>>>(hh, nullptr, 0, 0, H2,
                                                  W_hh_d, b_hh_d, ghE, H6, H2);
            gru_gate<<<grid_dgate, blk, 0, stream>>>(giE, ghE, hh, H2);
            logits_argmax<<<dim3(B), dim3(128), 0, stream>>>(hh, W_fc, b_fc, out, tok, t);
        }
    }
}

// Round 4
// 11088.136 us; speedup vs baseline: 1.7175x; 1.7175x over previous
//
#include <hip/hip_runtime.h>
#include <math.h>

#define B 512
#define S 64
#define T 32
#define E 512
#define H 1024
#define VOUTD 128
#define H2 (2*H)
#define H3 (3*H)
#define H6 (6*H)

typedef unsigned short ushortT;
typedef unsigned int uintT;
typedef __attribute__((ext_vector_type(8))) short short8;
typedef __attribute__((ext_vector_type(4))) float floatx4;

__device__ __forceinline__ float sigmoidf_(float x) { return 1.0f / (1.0f + expf(-x)); }

// ===========================================================================
// Split fp32 -> bf16 hi/lo planes. hi = trunc16(x), lo = trunc16(x - hi).
// ===========================================================================
__global__ __launch_bounds__(256) void split_bf16(
    const float4* __restrict__ x, uint2* __restrict__ hi, uint2* __restrict__ lo, int n4)
{
    int i = blockIdx.x * 256 + threadIdx.x;
    if (i >= n4) return;
    float4 v = x[i];
    uintT ux = __float_as_uint(v.x), uy = __float_as_uint(v.y);
    uintT uz = __float_as_uint(v.z), uw = __float_as_uint(v.w);
    uintT lx = __float_as_uint(v.x - __uint_as_float(ux & 0xFFFF0000u)) >> 16;
    uintT ly = __float_as_uint(v.y - __uint_as_float(uy & 0xFFFF0000u)) >> 16;
    uintT lz = __float_as_uint(v.z - __uint_as_float(uz & 0xFFFF0000u)) >> 16;
    uintT lw = __float_as_uint(v.w - __uint_as_float(uw & 0xFFFF0000u)) >> 16;
    hi[i] = make_uint2((ux >> 16) | (uy & 0xFFFF0000u), (uz >> 16) | (uw & 0xFFFF0000u));
    lo[i] = make_uint2(lx | (ly << 16), lz | (lw << 16));
}

__global__ __launch_bounds__(256) void zero16(uint4* __restrict__ p, int n)
{
    int i = blockIdx.x * 256 + threadIdx.x;
    if (i < n) p[i] = make_uint4(0u, 0u, 0u, 0u);
}

// ===========================================================================
// Split-bf16 MFMA GEMM for the recurrent (gh) matmuls, double-buffered LDS +
// split-K. C_part[p][M,N] = A[:, pK:(p+1)K] @ W[:, pK:(p+1)K]^T  (NO bias —
// b_hh is added in the gate). A,W given as bf16 hi/lo planes, row length K.
// Encoder fwd/bwd fusion: weight set selected by m-half (m0>=512 -> _b).
// Tile 128x128x32, 256 thr = 4 waves (2x2). grid = (N/128, M/128, parts).
// 3 MFMA terms: Ah*Bh + Ah*Bl + Al*Bh. Deterministic (no atomics).
// ===========================================================================
__global__ __launch_bounds__(256) void gemm_gh_split(
    const ushortT* __restrict__ Ahi, const ushortT* __restrict__ Alo,
    const ushortT* __restrict__ Whi_f, const ushortT* __restrict__ Wlo_f,
    const ushortT* __restrict__ Whi_b, const ushortT* __restrict__ Wlo_b,
    float* __restrict__ C, int N, int K, int parts, int Mtot)
{
    __shared__ ushortT sAh[2][128 * 32];
    __shared__ ushortT sAl[2][128 * 32];
    __shared__ ushortT sBh[2][128 * 32];
    __shared__ ushortT sBl[2][128 * 32];

    const int t    = threadIdx.x;
    const int lane = t & 63;
    const int w    = t >> 6;
    const int m0   = blockIdx.y * 128;
    const int n0   = blockIdx.x * 128;
    const int kLen  = K / parts;
    const int kBase = blockIdx.z * kLen;
    const bool bwd = (m0 >= B);
    const ushortT* Whi = bwd ? Whi_b : Whi_f;
    const ushortT* Wlo = bwd ? Wlo_b : Wlo_f;
    float* Cp = C + (size_t)blockIdx.z * Mtot * N;

    // Staging map: 16B chunk c = li*256 + t covers tile row c>>2, k-seg (c&3)*8.
    const ushortT* gAh[2]; const ushortT* gAl[2];
    const ushortT* gBh[2]; const ushortT* gBl[2];
    int ldsE[2];
#pragma unroll
    for (int li = 0; li < 2; ++li) {
        int c = li * 256 + t;
        int row = c >> 2;
        int segE = (c & 3) * 8;
        gAh[li] = Ahi + (long long)(m0 + row) * K + kBase + segE;
        gAl[li] = Alo + (long long)(m0 + row) * K + kBase + segE;
        gBh[li] = Whi + (long long)(n0 + row) * K + kBase + segE;
        gBl[li] = Wlo + (long long)(n0 + row) * K + kBase + segE;
        ldsE[li] = c * 8;
    }

    const int koff = (lane >> 4) * 8;
    const int mrow = (w >> 1) * 64 + (lane & 15);
    const int ncol = (w & 1) * 64 + (lane & 15);

    floatx4 acc[4][4];
#pragma unroll
    for (int i = 0; i < 4; ++i)
#pragma unroll
        for (int j = 0; j < 4; ++j) acc[i][j] = (floatx4){0.f, 0.f, 0.f, 0.f};

    const int nCh = kLen / 32;
    uint4 vAh[2], vAl[2], vBh[2], vBl[2];

    // prologue: chunk 0 -> buf 0
#pragma unroll
    for (int li = 0; li < 2; ++li) {
        vAh[li] = *(const uint4*)(gAh[li]);
        vAl[li] = *(const uint4*)(gAl[li]);
        vBh[li] = *(const uint4*)(gBh[li]);
        vBl[li] = *(const uint4*)(gBl[li]);
    }
#pragma unroll
    for (int li = 0; li < 2; ++li) {
        *(uint4*)&sAh[0][ldsE[li]] = vAh[li];
        *(uint4*)&sAl[0][ldsE[li]] = vAl[li];
        *(uint4*)&sBh[0][ldsE[li]] = vBh[li];
        *(uint4*)&sBl[0][ldsE[li]] = vBl[li];
    }
    __syncthreads();

    int p = 0;
    for (int ck = 0; ck < nCh; ++ck) {
        const bool hasNext = (ck + 1 < nCh);
        if (hasNext) {
            int k0 = (ck + 1) * 32;
#pragma unroll
            for (int li = 0; li < 2; ++li) {
                vAh[li] = *(const uint4*)(gAh[li] + k0);
                vAl[li] = *(const uint4*)(gAl[li] + k0);
                vBh[li] = *(const uint4*)(gBh[li] + k0);
                vBl[li] = *(const uint4*)(gBl[li] + k0);
            }
        }

        short8 ah[4], al[4], bh[4], bl[4];
#pragma unroll
        for (int i = 0; i < 4; ++i) {
            ah[i] = *(const short8*)&sAh[p][(mrow + i * 16) * 32 + koff];
            al[i] = *(const short8*)&sAl[p][(mrow + i * 16) * 32 + koff];
            bh[i] = *(const short8*)&sBh[p][(ncol + i * 16) * 32 + koff];
            bl[i] = *(const short8*)&sBl[p][(ncol + i * 16) * 32 + koff];
        }
#pragma unroll
        for (int i = 0; i < 4; ++i)
#pragma unroll
            for (int j = 0; j < 4; ++j) {
                acc[i][j] = __builtin_amdgcn_mfma_f32_16x16x32_bf16(ah[i], bh[j], acc[i][j], 0, 0, 0);
                acc[i][j] = __builtin_amdgcn_mfma_f32_16x16x32_bf16(ah[i], bl[j], acc[i][j], 0, 0, 0);
                acc[i][j] = __builtin_amdgcn_mfma_f32_16x16x32_bf16(al[i], bh[j], acc[i][j], 0, 0, 0);
            }

        if (hasNext) {
            __syncthreads();       // everyone done reading buf p
            int q = p ^ 1;
#pragma unroll
            for (int li = 0; li < 2; ++li) {
                *(uint4*)&sAh[q][ldsE[li]] = vAh[li];
                *(uint4*)&sAl[q][ldsE[li]] = vAl[li];
                *(uint4*)&sBh[q][ldsE[li]] = vBh[li];
                *(uint4*)&sBl[q][ldsE[li]] = vBl[li];
            }
            __syncthreads();       // writes visible for next iter
            p = q;
        }
    }

    // epilogue: C/D layout col=lane&15, row=(lane>>4)*4+reg
#pragma unroll
    for (int j = 0; j < 4; ++j) {
        int col = n0 + (w & 1) * 64 + j * 16 + (lane & 15);
#pragma unroll
        for (int i = 0; i < 4; ++i) {
            int rowb = m0 + (w >> 1) * 64 + i * 16 + (lane >> 4) * 4;
#pragma unroll
            for (int r = 0; r < 4; ++r)
                Cp[(long long)(rowb + r) * N + col] = acc[i][j][r];
        }
    }
}

// ===========================================================================
// Encoder gate: gi gathered from precomputed tables (tiny vocab). Sums the 2
// split-K gh parts + b_hh, applies GRU gate, writes h fp32 + bf16 planes.
// ===========================================================================
__global__ __launch_bounds__(256) void gru_gate_enc(
    const float* __restrict__ giTabF, const float* __restrict__ giTabB,
    const int* __restrict__ src, int s,
    const float* __restrict__ gh, long long partStride,
    const float* __restrict__ bhF, const float* __restrict__ bhB,
    float* __restrict__ h, ushortT* __restrict__ h_hi, ushortT* __restrict__ h_lo)
{
    int i = blockIdx.x * 256 + threadIdx.x;     // over 2B*H
    int r = i >> 10;          // /H
    int j = i & (H - 1);
    int b = r & (B - 1);
    bool fwd = (r < B);
    int tk = src[b * S + (fwd ? s : (S - 1 - s))];
    const float* gi = (fwd ? giTabF : giTabB) + (size_t)tk * H3;
    const float* bh = fwd ? bhF : bhB;
    const float* g0 = gh + (size_t)r * H3;
    const float* g1 = g0 + partStride;
    float ghr = g0[j]         + g1[j]         + bh[j];
    float ghz = g0[H + j]     + g1[H + j]     + bh[H + j];
    float ghn = g0[2 * H + j] + g1[2 * H + j] + bh[2 * H + j];
    float rr = sigmoidf_(gi[j] + ghr);
    float z  = sigmoidf_(gi[H + j] + ghz);
    float n  = tanhf(gi[2 * H + j] + rr * ghn);
    float hnew = (1.0f - z) * n + z * h[i];
    h[i] = hnew;
    uintT u = __float_as_uint(hnew);
    h_hi[i] = (ushortT)(u >> 16);
    h_lo[i] = (ushortT)(__float_as_uint(hnew - __uint_as_float(u & 0xFFFF0000u)) >> 16);
}

// Decoder gate: same, Hd=2H, gi from giTabD[tok[b]].
__global__ __launch_bounds__(256) void gru_gate_dec(
    const float* __restrict__ giTabD, const int* __restrict__ tok,
    const float* __restrict__ gh, long long partStride,
    const float* __restrict__ bh,
    float* __restrict__ h, ushortT* __restrict__ h_hi, ushortT* __restrict__ h_lo)
{
    int i = blockIdx.x * 256 + threadIdx.x;     // over B*2H
    int b = i >> 11;
    int j = i & (H2 - 1);
    const float* gi = giTabD + (size_t)tok[b] * H6;
    const float* g0 = gh + (size_t)b * H6;
    const float* g1 = g0 + partStride;
    float ghr = g0[j]          + g1[j]          + bh[j];
    float ghz = g0[H2 + j]     + g1[H2 + j]     + bh[H2 + j];
    float ghn = g0[2 * H2 + j] + g1[2 * H2 + j] + bh[2 * H2 + j];
    float rr = sigmoidf_(gi[j] + ghr);
    float z  = sigmoidf_(gi[H2 + j] + ghz);
    float n  = tanhf(gi[2 * H2 + j] + rr * ghn);
    float hnew = (1.0f - z) * n + z * h[i];
    h[i] = hnew;
    uintT u = __float_as_uint(hnew);
    h_hi[i] = (ushortT)(u >> 16);
    h_lo[i] = (ushortT)(__float_as_uint(hnew - __uint_as_float(u & 0xFFFF0000u)) >> 16);
}

// hh[b,0:H]=h_f[b], hh[b,H:2H]=h_b[b] (+ bf16 planes); tok[b]=tgt[b,0]
__global__ __launch_bounds__(256) void init_hh_tok_split(
    const float* __restrict__ h_f, const float* __restrict__ h_b,
    const int* __restrict__ tgt, float* __restrict__ hh,
    ushortT* __restrict__ hh_hi, ushortT* __restrict__ hh_lo, int* __restrict__ tok)
{
    int i = blockIdx.x * blockDim.x + threadIdx.x;   // over B*2H
    int b = i >> 11;
    int j = i & 2047;
    float v = (j < H) ? h_f[(size_t)b * H + j] : h_b[(size_t)b * H + (j - H)];
    hh[i] = v;
    uintT u = __float_as_uint(v);
    hh_hi[i] = (ushortT)(u >> 16);
    hh_lo[i] = (ushortT)(__float_as_uint(v - __uint_as_float(u & 0xFFFF0000u)) >> 16);
    if (j == 0) tok[b] = tgt[b * T];
}

// ===========================================================================
// logits = hh @ W_fc^T + b_fc (V=128); out[b,t,:]; tok[b]=argmax (first-idx ties)
// ===========================================================================
__global__ __launch_bounds__(128) void logits_argmax(
    const float* __restrict__ hh, const float* __restrict__ W_fc,
    const float* __restrict__ b_fc, float* __restrict__ out,
    int* __restrict__ tok, int t)
{
    __shared__ float sh[H2];
    __shared__ float svals[128];
    __shared__ int   sidx[128];
    const int b = blockIdx.x;
    const int v = threadIdx.x;
    const float* hrow = hh + (size_t)b * H2;
    for (int i = v; i < H2 / 4; i += 128)
        ((float4*)sh)[i] = ((const float4*)hrow)[i];
    __syncthreads();
    const float* wrow = W_fc + (size_t)v * H2;
    float acc = b_fc[v];
    for (int k = 0; k < H2; k += 4) {
        float4 w4 = *(const float4*)(wrow + k);
        float4 h4 = *(const float4*)(sh + k);
        acc += w4.x * h4.x + w4.y * h4.y + w4.z * h4.z + w4.w * h4.w;
    }
    out[(size_t)b * ((T - 1) * VOUTD) + (size_t)t * VOUTD + v] = acc;

    svals[v] = acc; sidx[v] = v;
    __syncthreads();
    for (int off = 64; off > 0; off >>= 1) {
        if (v < off) {
            float ov = svals[v + off]; int oi = sidx[v + off];
            if (ov > svals[v] || (ov == svals[v] && oi < sidx[v])) {
                svals[v] = ov; sidx[v] = oi;
            }
        }
        __syncthreads();
    }
    if (v == 0) tok[b] = sidx[0];
}

// ===========================================================================
// fp32 vector GEMM (R1-proven): C[M,N] = A @ W^T + bias. Used for the tiny
// gi-table precomputes (exact fp32) and as full fallback path.
// ===========================================================================
__global__ __launch_bounds__(256) void gemm_bias(
    const float* __restrict__ Abase,
    const int* __restrict__ idx, int idxStride, int idxOff, int lda,
    const float* __restrict__ W, const float* __restrict__ bias,
    float* __restrict__ C, int N, int K)
{
    __shared__ float As[16][68];
    __shared__ float Ws[16][68];
    const int t = threadIdx.x;
    const int m0 = blockIdx.y * 64, n0 = blockIdx.x * 64;
    const int lr = t >> 2, lc = (t & 3) << 2;
    const int tx = t & 15, ty = t >> 4;
    const int tn0 = tx << 2, tm0 = ty << 2;
    const int arow = m0 + lr;
    const float* Aptr = idx ? (Abase + (size_t)idx[arow * idxStride + idxOff] * lda)
                            : (Abase + (size_t)arow * lda);
    const float* Wptr = W + (size_t)(n0 + lr) * K;
    float acc[4][4] = {{0.f}};
    for (int k0 = 0; k0 < K; k0 += 16) {
        float4 a4 = *(const float4*)(Aptr + k0 + lc);
        float4 w4 = *(const float4*)(Wptr + k0 + lc);
        __syncthreads();
        As[lc+0][lr] = a4.x; As[lc+1][lr] = a4.y; As[lc+2][lr] = a4.z; As[lc+3][lr] = a4.w;
        Ws[lc+0][lr] = w4.x; Ws[lc+1][lr] = w4.y; Ws[lc+2][lr] = w4.z; Ws[lc+3][lr] = w4.w;
        __syncthreads();
#pragma unroll
        for (int kk = 0; kk < 16; ++kk) {
            float4 av = *(const float4*)&As[kk][tm0];
            float4 wv = *(const float4*)&Ws[kk][tn0];
            float am[4] = {av.x, av.y, av.z, av.w};
            float wn[4] = {wv.x, wv.y, wv.z, wv.w};
#pragma unroll
            for (int i = 0; i < 4; ++i)
#pragma unroll
                for (int j = 0; j < 4; ++j) acc[i][j] += am[i] * wn[j];
        }
    }
    const float b0 = bias[n0+tn0], b1 = bias[n0+tn0+1], b2 = bias[n0+tn0+2], b3 = bias[n0+tn0+3];
#pragma unroll
    for (int i = 0; i < 4; ++i) {
        float4 o = make_float4(acc[i][0]+b0, acc[i][1]+b1, acc[i][2]+b2, acc[i][3]+b3);
        *(float4*)(C + (size_t)(m0 + tm0 + i) * N + n0 + tn0) = o;
    }
}

__global__ __launch_bounds__(256) void gemm_enc(
    const float* __restrict__ Abase, int lda, int K,
    const int* __restrict__ srcIdx, int s,
    const float* __restrict__ W1, const float* __restrict__ bias1,
    const float* __restrict__ W2, const float* __restrict__ bias2,
    float* __restrict__ C, int N)
{
    __shared__ float As[16][68];
    __shared__ float Ws[16][68];
    const int t = threadIdx.x;
    const int m0 = blockIdx.y * 64, n0 = blockIdx.x * 64;
    const bool bwd = (m0 >= B);
    const float* W = bwd ? W2 : W1;
    const float* bias = bwd ? bias2 : bias1;
    const int lr = t >> 2, lc = (t & 3) << 2;
    const int tx = t & 15, ty = t >> 4;
    const int tn0 = tx << 2, tm0 = ty << 2;
    const int arow = m0 + lr;
    const float* Aptr;
    if (srcIdx) {
        int r = arow & (B - 1);
        int sidx = bwd ? (S - 1 - s) : s;
        Aptr = Abase + (size_t)srcIdx[r * S + sidx] * lda;
    } else Aptr = Abase + (size_t)arow * lda;
    const float* Wptr = W + (size_t)(n0 + lr) * K;
    float acc[4][4] = {{0.f}};
    for (int k0 = 0; k0 < K; k0 += 16) {
        float4 a4 = *(const float4*)(Aptr + k0 + lc);
        float4 w4 = *(const float4*)(Wptr + k0 + lc);
        __syncthreads();
        As[lc+0][lr] = a4.x; As[lc+1][lr] = a4.y; As[lc+2][lr] = a4.z; As[lc+3][lr] = a4.w;
        Ws[lc+0][lr] = w4.x; Ws[lc+1][lr] = w4.y; Ws[lc+2][lr] = w4.z; Ws[lc+3][lr] = w4.w;
        __syncthreads();
#pragma unroll
        for (int kk = 0; kk < 16; ++kk) {
            float4 av = *(const float4*)&As[kk][tm0];
            float4 wv = *(const float4*)&Ws[kk][tn0];
            float am[4] = {av.x, av.y, av.z, av.w};
            float wn[4] = {wv.x, wv.y, wv.z, wv.w};
#pragma unroll
            for (int i = 0; i < 4; ++i)
#pragma unroll
                for (int j = 0; j < 4; ++j) acc[i][j] += am[i] * wn[j];
        }
    }
    const float b0 = bias[n0+tn0], b1 = bias[n0+tn0+1], b2 = bias[n0+tn0+2], b3 = bias[n0+tn0+3];
#pragma unroll
    for (int i = 0; i < 4; ++i) {
        float4 o = make_float4(acc[i][0]+b0, acc[i][1]+b1, acc[i][2]+b2, acc[i][3]+b3);
        *(float4*)(C + (size_t)(m0 + tm0 + i) * N + n0 + tn0) = o;
    }
}

__global__ __launch_bounds__(256) void gru_gate(
    const float* __restrict__ gi, const float* __restrict__ gh,
    float* __restrict__ h, int Hd)
{
    int i = blockIdx.x * blockDim.x + threadIdx.x;
    int b = i / Hd, j = i - b * Hd;
    const float* gib = gi + (size_t)b * 3 * Hd;
    const float* ghb = gh + (size_t)b * 3 * Hd;
    float r = sigmoidf_(gib[j] + ghb[j]);
    float z = sigmoidf_(gib[Hd + j] + ghb[Hd + j]);
    float n = tanhf(gib[2 * Hd + j] + r * ghb[2 * Hd + j]);
    h[i] = (1.0f - z) * n + z * h[i];
}

__global__ __launch_bounds__(256) void init_hh_tok(
    const float* __restrict__ h_f, const float* __restrict__ h_b,
    const int* __restrict__ tgt, float* __restrict__ hh, int* __restrict__ tok)
{
    int i = blockIdx.x * blockDim.x + threadIdx.x;
    int b = i >> 11, j = i & 2047;
    hh[i] = (j < H) ? h_f[(size_t)b * H + j] : h_b[(size_t)b * H + (j - H)];
    if (j == 0) tok[b] = tgt[b * T];
}

// ===========================================================================
extern "C" void kernel_launch(void* const* d_in, const int* in_sizes, int n_in,
                              void* d_out, int out_size, void* d_ws, size_t ws_size,
                              hipStream_t stream)
{
    const int*   src     = (const int*)d_in[0];
    const int*   tgt     = (const int*)d_in[1];
    const float* enc_emb = (const float*)d_in[2];
    const float* dec_emb = (const float*)d_in[3];
    const float* W_ih_f  = (const float*)d_in[4];
    const float* W_hh_f  = (const float*)d_in[5];
    const float* b_ih_f  = (const float*)d_in[6];
    const float* b_hh_f  = (const float*)d_in[7];
    const float* W_ih_b  = (const float*)d_in[8];
    const float* W_hh_b  = (const float*)d_in[9];
    const float* b_ih_b  = (const float*)d_in[10];
    const float* b_hh_b  = (const float*)d_in[11];
    const float* W_ih_d  = (const float*)d_in[12];
    const float* W_hh_d  = (const float*)d_in[13];
    const float* b_ih_d  = (const float*)d_in[14];
    const float* b_hh_d  = (const float*)d_in[15];
    const float* W_fc    = (const float*)d_in[16];
    const float* b_fc    = (const float*)d_in[17];
    float* out = (float*)d_out;

    // ---------------- workspace layout ----------------
    char* base = (char*)d_ws;
    size_t off = 0;
    auto alloc = [&](size_t bytes) { char* p = base + off; off += (bytes + 255) & ~(size_t)255; return p; };

    float*   hE     = (float*)  alloc((size_t)2 * B * H * 4);      // zeroed with planes below
    ushortT* hE_hi  = (ushortT*)alloc((size_t)2 * B * H * 2);
    ushortT* hE_lo  = (ushortT*)alloc((size_t)2 * B * H * 2);
    float*   hh     = (float*)  alloc((size_t)B * H2 * 4);
    ushortT* hh_hi  = (ushortT*)alloc((size_t)B * H2 * 2);
    ushortT* hh_lo  = (ushortT*)alloc((size_t)B * H2 * 2);
    float*   ghE    = (float*)  alloc((size_t)2 * 2 * B * H3 * 4); // 2 split-K parts (enc 2B x 3H; dec B x 6H)
    float*   giTabF = (float*)  alloc((size_t)VOUTD * H3 * 4);
    float*   giTabB = (float*)  alloc((size_t)VOUTD * H3 * 4);
    float*   giTabD = (float*)  alloc((size_t)VOUTD * H6 * 4);
    ushortT* Whhf_hi = (ushortT*)alloc((size_t)H3 * H * 2);
    ushortT* Whhf_lo = (ushortT*)alloc((size_t)H3 * H * 2);
    ushortT* Whhb_hi = (ushortT*)alloc((size_t)H3 * H * 2);
    ushortT* Whhb_lo = (ushortT*)alloc((size_t)H3 * H * 2);
    ushortT* Whhd_hi = (ushortT*)alloc((size_t)H6 * H2 * 2);
    ushortT* Whhd_lo = (ushortT*)alloc((size_t)H6 * H2 * 2);
    int*     tok    = (int*)    alloc((size_t)B * 4);
    // fallback-path extra buffer (overlays split-path region when used)
    float*   giE    = ghE;                                         // fallback gi (2B x 3H fits in part0+)
    size_t required = off;

    dim3 blk(256);

    if (ws_size >= required) {
        // =================== split-bf16 MFMA path ===================
        {   // zero hE + hE_hi + hE_lo (contiguous)
            size_t zbytes = (size_t)2 * B * H * 4 + 2 * ((size_t)2 * B * H * 2);
            int n16 = (int)(zbytes / 16);
            zero16<<<dim3((n16 + 255) / 256), blk, 0, stream>>>((uint4*)hE, n16);
        }
        // split only the recurrent weights
        auto split = [&](const float* x, ushortT* hi, ushortT* lo, size_t n) {
            int n4 = (int)(n / 4);
            split_bf16<<<dim3((n4 + 255) / 256), blk, 0, stream>>>(
                (const float4*)x, (uint2*)hi, (uint2*)lo, n4);
        };
        split(W_hh_f, Whhf_hi, Whhf_lo, (size_t)H3 * H);
        split(W_hh_b, Whhb_hi, Whhb_lo, (size_t)H3 * H);
        split(W_hh_d, Whhd_hi, Whhd_lo, (size_t)H6 * H2);

        // gi tables (exact fp32): emb @ W_ih^T + b_ih, M=128
        gemm_bias<<<dim3(H3 / 64, VOUTD / 64), blk, 0, stream>>>(
            enc_emb, nullptr, 0, 0, E, W_ih_f, b_ih_f, giTabF, H3, E);
        gemm_bias<<<dim3(H3 / 64, VOUTD / 64), blk, 0, stream>>>(
            enc_emb, nullptr, 0, 0, E, W_ih_b, b_ih_b, giTabB, H3, E);
        gemm_bias<<<dim3(H6 / 64, VOUTD / 64), blk, 0, stream>>>(
            dec_emb, nullptr, 0, 0, E, W_ih_d, b_ih_d, giTabD, H6, E);

        // ---------------- Encoder: 64 steps ----------------
        dim3 grid_e(H3 / 128, (2 * B) / 128, 2);     // 24 x 8 x 2 = 384 blocks
        dim3 grid_gate((2 * B * H) / 256);
        const long long encPart = (long long)(2 * B) * H3;
        for (int s = 0; s < S; ++s) {
            gemm_gh_split<<<grid_e, blk, 0, stream>>>(
                hE_hi, hE_lo, Whhf_hi, Whhf_lo, Whhb_hi, Whhb_lo,
                ghE, H3, H, 2, 2 * B);
            gru_gate_enc<<<grid_gate, blk, 0, stream>>>(
                giTabF, giTabB, src, s, ghE, encPart, b_hh_f, b_hh_b,
                hE, hE_hi, hE_lo);
        }

        init_hh_tok_split<<<dim3((B * H2) / 256), blk, 0, stream>>>(
            hE, hE + (size_t)B * H, tgt, hh, hh_hi, hh_lo, tok);

        // ---------------- Decoder: 31 steps ----------------
        dim3 grid_d(H6 / 128, B / 128, 2);           // 48 x 4 x 2 = 384 blocks
        dim3 grid_dgate((B * H2) / 256);
        const long long decPart = (long long)B * H6;
        for (int t = 0; t < T - 1; ++t) {
            gemm_gh_split<<<grid_d, blk, 0, stream>>>(
                hh_hi, hh_lo, Whhd_hi, Whhd_lo, Whhd_hi, Whhd_lo,
                ghE, H6, H2, 2, B);
            gru_gate_dec<<<grid_dgate, blk, 0, stream>>>(
                giTabD, tok, ghE, decPart, b_hh_d, hh, hh_hi, hh_lo);
            logits_argmax<<<dim3(B), dim3(128), 0, stream>>>(hh, W_fc, b_fc, out, tok, t);
        }
    } else {
        // =================== fp32 fallback (R1-proven path) ===================
        {
            size_t zbytes = (size_t)2 * B * H * 4;
            int n16 = (int)(zbytes / 16);
            zero16<<<dim3((n16 + 255) / 256), blk, 0, stream>>>((uint4*)hE, n16);
        }
        float* ghF = giE + (size_t)2 * B * H3;   // second half of ghE region
        dim3 grid_gi(H3 / 64, (2 * B) / 64);
        dim3 grid_gate((2 * B * H) / 256);
        for (int s = 0; s < S; ++s) {
            gemm_enc<<<grid_gi, blk, 0, stream>>>(enc_emb, E, E, src, s,
                                                  W_ih_f, b_ih_f, W_ih_b, b_ih_b, giE, H3);
            gemm_enc<<<grid_gi, blk, 0, stream>>>(hE, H, H, nullptr, 0,
                                                  W_hh_f, b_hh_f, W_hh_b, b_hh_b, ghF, H3);
            gru_gate<<<grid_gate, blk, 0, stream>>>(giE, ghF, hE, H);
        }
        init_hh_tok<<<dim3((B * H2) / 256), blk, 0, stream>>>(hE, hE + (size_t)B * H, tgt, hh, tok);
        dim3 grid_d(H6 / 64, B / 64);
        dim3 grid_dgate((B * H2) / 256);
        for (int t = 0; t < T - 1; ++t) {
            gemm_bias<<<grid_d, blk, 0, stream>>>(dec_emb, tok, 1, 0, E,
                                                  W_ih_d, b_ih_d, giE, H6, E);
            gemm_bias<<<grid_d, blk, 0, stream>>>(hh, nullptr, 0, 0, H2,
                                                  W_hh_d, b_hh_d, ghF, H6, H2);
            gru_gate<<<grid_dgate, blk, 0, stream>>>(giE, ghF, hh, H2);
            logits_argmax<<<dim3(B), dim3(128), 0, stream>>>(hh, W_fc, b_fc, out, tok, t);
        }
    }
}